// Round 23
// baseline (186.997 us; speedup 1.0000x reference)
//
#include <hip/hip_runtime.h>
#include <hip/hip_bf16.h>

typedef __bf16 bf16;
typedef __attribute__((__ext_vector_type__(4))) __bf16 bf16x4;
typedef __attribute__((__ext_vector_type__(8))) __bf16 bf16x8;
typedef __attribute__((__ext_vector_type__(4))) float f32x4;

#define MFMA16(a, b, c) __builtin_amdgcn_mfma_f32_16x16x32_bf16(a, b, c, 0, 0, 0)

static __device__ __forceinline__ bf16 f2b(float f) { return (bf16)f; }

// async global->LDS, 16B per lane. LDS dest: wave-uniform base + lane*16 (HW).
static __device__ __forceinline__ void gload16(const void* g, void* l) {
    __builtin_amdgcn_global_load_lds(
        (const __attribute__((address_space(1))) int*)g,
        (__attribute__((address_space(3))) int*)l, 16, 0, 0);
}

// ---------------------------------------------------------------------------
// xcast: f32 -> bf16 bulk cast (X -> Xb), 16 elems/thread
// ---------------------------------------------------------------------------
__global__ __launch_bounds__(256) void xcast(
    const float* __restrict__ in, bf16* __restrict__ out)
{
    size_t i = ((size_t)blockIdx.x * 256 + threadIdx.x) * 16;
    float4 a0 = *(const float4*)(in + i);
    float4 a1 = *(const float4*)(in + i + 4);
    float4 a2 = *(const float4*)(in + i + 8);
    float4 a3 = *(const float4*)(in + i + 12);
    bf16x8 p0, p1;
    p0[0] = f2b(a0.x); p0[1] = f2b(a0.y); p0[2] = f2b(a0.z); p0[3] = f2b(a0.w);
    p0[4] = f2b(a1.x); p0[5] = f2b(a1.y); p0[6] = f2b(a1.z); p0[7] = f2b(a1.w);
    p1[0] = f2b(a2.x); p1[1] = f2b(a2.y); p1[2] = f2b(a2.z); p1[3] = f2b(a2.w);
    p1[4] = f2b(a3.x); p1[5] = f2b(a3.y); p1[6] = f2b(a3.z); p1[7] = f2b(a3.w);
    *(bf16x8*)(out + i) = p0;
    *(bf16x8*)(out + i + 8) = p1;
}

// ---------------------------------------------------------------------------
// cast + transpose: in (R x Cc) f32 row-major -> out (Cc x R) bf16 row-major
// ---------------------------------------------------------------------------
__global__ __launch_bounds__(256) void cast_transpose(
    const float* __restrict__ in, bf16* __restrict__ out, int R, int Cc)
{
    __shared__ float tile[32][33];
    const int c0 = blockIdx.x * 32, r0 = blockIdx.y * 32;
    const int tx = threadIdx.x & 31, ty = threadIdx.x >> 5;
#pragma unroll
    for (int i = ty; i < 32; i += 8)
        tile[i][tx] = in[(size_t)(r0 + i) * Cc + c0 + tx];
    __syncthreads();
#pragma unroll
    for (int i = ty; i < 32; i += 8)
        out[(size_t)(c0 + i) * R + r0 + tx] = f2b(tile[tx][i]);
}

// ---------------------------------------------------------------------------
// QKV GEMM (m97-style): Xb (8192x1024 bf16) @ WqkvT^T + bias -> Qb,Kb,Vt
//   Q is PRE-SCALED by 1/sqrt(64)*log2(e) so attn works in log2 domain free.
// ---------------------------------------------------------------------------
#define QSCALE (0.125f * 1.44269504f)

__global__ __launch_bounds__(256) void qkv_gemm(
    const bf16* __restrict__ Xb, const bf16* __restrict__ Wt,
    const float* __restrict__ bias,
    bf16* __restrict__ Qb, bf16* __restrict__ Kb, bf16* __restrict__ Vt)
{
    __shared__ __align__(16) bf16 As[128 * 32];
    __shared__ __align__(16) bf16 Bs[128 * 32];
    const int m0 = blockIdx.x * 128, n0 = blockIdx.y * 128;
    const int tid = threadIdx.x, lane = tid & 63, w = tid >> 6;
    const int wr = (w >> 1) * 64, wc = (w & 1) * 64;
    const int lg = lane >> 4, lr = lane & 15;
    const int srow = tid >> 2, scol = (tid & 3) * 8;
    f32x4 acc[4][4] = {};

    for (int k0 = 0; k0 < 1024; k0 += 32) {
#pragma unroll
        for (int half = 0; half < 2; ++half) {
            const int r = srow + half * 64;
            gload16(Xb + (size_t)(m0 + r) * 1024 + k0 + scol,
                    As + half * 2048 + w * 512);
            gload16(Wt + (size_t)(n0 + r) * 1024 + k0 + scol,
                    Bs + half * 2048 + w * 512);
        }
        __syncthreads();

        bf16x8 af[4], bfr[4];
#pragma unroll
        for (int m = 0; m < 4; ++m)
            af[m] = *(const bf16x8*)(As + (wr + m * 16 + lr) * 32 + lg * 8);
#pragma unroll
        for (int n = 0; n < 4; ++n)
            bfr[n] = *(const bf16x8*)(Bs + (wc + n * 16 + lr) * 32 + lg * 8);
#pragma unroll
        for (int m = 0; m < 4; ++m)
#pragma unroll
            for (int n = 0; n < 4; ++n)
                acc[m][n] = MFMA16(af[m], bfr[n], acc[m][n]);
        __syncthreads();
    }

#pragma unroll
    for (int m = 0; m < 4; ++m)
#pragma unroll
        for (int n = 0; n < 4; ++n) {
            int gn = n0 + wc + n * 16 + lr;
            int which = gn >> 10, cc = gn & 1023;
            int h = cc >> 6, d = cc & 63;
            float bv = bias[gn];
            if (which == 2) {
                int gm0 = m0 + wr + m * 16 + lg * 4;
                int b = gm0 >> 11, t0 = gm0 & 2047;
                size_t bh = (size_t)(b * 16 + h);
                bf16x4 pk;
#pragma unroll
                for (int j = 0; j < 4; ++j) pk[j] = f2b(acc[m][n][j] + bv);
                *(bf16x4*)(Vt + (bh * 64 + d) * 2048 + t0) = pk;
            } else {
#pragma unroll
                for (int j = 0; j < 4; ++j) {
                    int gm = m0 + wr + m * 16 + lg * 4 + j;
                    int b = gm >> 11, t = gm & 2047;
                    size_t bh = (size_t)(b * 16 + h);
                    if (which == 0)
                        Qb[(bh * 2048 + t) * 64 + d] =
                            f2b((acc[m][n][j] + bv) * QSCALE);
                    else
                        Kb[(bh * 2048 + t) * 64 + d] = f2b(acc[m][n][j] + bv);
                }
            }
        }
}

// ---------------------------------------------------------------------------
// Flash attention (causal), triangle-paired, swapped QK^T, XCD-colocated.
// 8-WAVE blocks (512 thr): waves 0-3 compute q-tile B strips, waves 4-7
// q-tile A strips (idle-barrier when it > ia) -> per-iteration critical path
// is ONE phase, not two. Staging: 1x16B K + 1x16B V per thread.
// Swizzled [64][64] K/V (verified formulas); no-max softmax; l via ones-MFMA;
// T5 setprio. LDS = 8K+8K+16K(Ps[8]) = 32768 B -> 4 blocks x 512 thr =
// 2048 threads/CU (hardware max).
// ---------------------------------------------------------------------------
__global__ __launch_bounds__(512, 8) void attn(
    const bf16* __restrict__ Qb, const bf16* __restrict__ Kb,
    const bf16* __restrict__ Vt, bf16* __restrict__ Yb)
{
    __shared__ __align__(16) bf16 Ks[64 * 64];
    __shared__ __align__(16) bf16 Vs[64 * 64];
    __shared__ __align__(16) bf16 Ps[8][16 * 64];
    const int lid = blockIdx.x;                  // 0..1023
    const int xcd = lid & 7, idx = lid >> 3;     // round-robin XCD assumption
    const int bh = xcd * 8 + (idx >> 4);         // 8 bh per XCD
    const int pair = idx & 15;                   // 0..15
    const int ia = pair, ib = 31 - pair;
    const int tid = threadIdx.x, lane = tid & 63, w = tid >> 6;   // w: 0..7
    const int g = w >> 2;                        // 0 = tile B, 1 = tile A
    const int wl = w & 3;                        // strip within tile
    const int qt = g ? ia : ib;                  // this wave's q-tile index
    const int q0w = qt * 64;
    const int lg = lane >> 4, lr = lane & 15;

    const bf16* qr = Qb + ((size_t)bh * 2048 + q0w + wl * 16 + lr) * 64;
    bf16x8 qf0 = *(const bf16x8*)(qr + lg * 8);
    bf16x8 qf1 = *(const bf16x8*)(qr + 32 + lg * 8);

    const bf16 one = (bf16)1.0f;
    const bf16x8 vones = {one, one, one, one, one, one, one, one};

    f32x4 o[4] = {};                             // o[n][j]: d=n*16+lr, q=wl*16+lg*4+j
    f32x4 oL = {};                               // l accumulator (ones-MFMA)

    // staging: thread -> one 16B chunk of K and of V. row = tid>>3, c = tid&7.
    const int srow = tid >> 3;                   // 0..63
    const int sc = tid & 7;                      // chunk 0..7
    const int sp = sc * 8;                       // source col (elems)
    const int dst = srow * 64 + ((sc ^ (srow & 7)) << 3);    // swizzled dest
    // read-side swizzled column offsets; row&7 == lr&7
    const int swa = ((lg ^ (lr & 7)) << 3);
    const int swb = (((lg + 4) ^ (lr & 7)) << 3);
    // Ps write slot (verified)
    const int pbase = lr * 64 + (lg & 1) * 4;

    // P-frag build via per-wave swizzled LDS. No max tracking.
    auto sm = [&](f32x4 (&s)[4], bool diag, bf16x8& pf0, bf16x8& pf1) {
        if (diag) {
            const int qloc = wl * 16 + lr;
#pragma unroll
            for (int n = 0; n < 4; ++n)
#pragma unroll
                for (int j = 0; j < 4; ++j)
                    if (n * 16 + lg * 4 + j > qloc) s[n][j] = -1e30f;
        }
#pragma unroll
        for (int n = 0; n < 4; ++n) {
            bf16x4 pk;
#pragma unroll
            for (int j = 0; j < 4; ++j)
                pk[j] = f2b(exp2f(s[n][j]));
            *(bf16x4*)(&Ps[w][pbase + (((n * 2 + (lg >> 1)) ^ (lr & 7)) << 3)]) = pk;
        }
        pf0 = *(const bf16x8*)(&Ps[w][lr * 64 + swa]);
        pf1 = *(const bf16x8*)(&Ps[w][lr * 64 + swb]);
    };

    const int ntiles = ib + 1;
    for (int it = 0; it < ntiles; ++it) {
        const int j0 = it * 64;
        // stage: 1x16B K + 1x16B V per thread, immediate swizzled commit
        int4 kr = *(const int4*)(Kb + ((size_t)bh * 2048 + j0 + srow) * 64 + sp);
        int4 vr = *(const int4*)(Vt + ((size_t)bh * 64 + srow) * 2048 + j0 + sp);
        *(int4*)(Ks + dst) = kr;
        *(int4*)(Vs + dst) = vr;
        __syncthreads();

        const bool active = (g == 0) || (it <= ia);
        if (active) {
            // QK^T for this wave's tile strip; MFMA under setprio(1)
            f32x4 s[4];
            __builtin_amdgcn_s_setprio(1);
#pragma unroll
            for (int n = 0; n < 4; ++n) {
                const bf16* krow = Ks + (n * 16 + lr) * 64;
                bf16x8 kf0 = *(const bf16x8*)(krow + swa);
                bf16x8 kf1 = *(const bf16x8*)(krow + swb);
                f32x4 z = {};
                z = MFMA16(kf0, qf0, z);
                z = MFMA16(kf1, qf1, z);
                s[n] = z;
            }
            __builtin_amdgcn_s_setprio(0);

            bf16x8 pf0, pf1;
            sm(s, it == qt, pf0, pf1);

            __builtin_amdgcn_s_setprio(1);
            oL = MFMA16(pf0, vones, oL);
            oL = MFMA16(pf1, vones, oL);
#pragma unroll
            for (int n = 0; n < 4; ++n) {
                const bf16* vrow = Vs + (n * 16 + lr) * 64;
                bf16x8 vf0 = *(const bf16x8*)(vrow + swa);
                bf16x8 vf1 = *(const bf16x8*)(vrow + swb);
                o[n] = MFMA16(pf0, vf0, o[n]);
                o[n] = MFMA16(pf1, vf1, o[n]);
            }
            __builtin_amdgcn_s_setprio(0);
        }
        __syncthreads();
    }

    const int b = bh >> 4, h = bh & 15;
    float lj[4];
#pragma unroll
    for (int j = 0; j < 4; ++j) lj[j] = 1.f / oL[j];
#pragma unroll
    for (int n = 0; n < 4; ++n)
#pragma unroll
        for (int j = 0; j < 4; ++j) {
            int qr2 = q0w + wl * 16 + lg * 4 + j;
            Yb[((size_t)b * 2048 + qr2) * 1024 + h * 64 + n * 16 + lr] =
                f2b(o[n][j] * lj[j]);
        }
}

// ---------------------------------------------------------------------------
// Out GEMM (m97-style): Yb (8192x1024 bf16) @ WoutT^T + bias -> Out f32
// ---------------------------------------------------------------------------
__global__ __launch_bounds__(256) void out_gemm(
    const bf16* __restrict__ Y, const bf16* __restrict__ Wt,
    const float* __restrict__ bias, float* __restrict__ Out)
{
    __shared__ __align__(16) bf16 As[128 * 32];
    __shared__ __align__(16) bf16 Bs[128 * 32];
    const int m0 = blockIdx.x * 128, n0 = blockIdx.y * 128;
    const int tid = threadIdx.x, lane = tid & 63, w = tid >> 6;
    const int wr = (w >> 1) * 64, wc = (w & 1) * 64;
    const int lg = lane >> 4, lr = lane & 15;
    const int srow = tid >> 2, scol = (tid & 3) * 8;
    f32x4 acc[4][4] = {};

    for (int k0 = 0; k0 < 1024; k0 += 32) {
#pragma unroll
        for (int half = 0; half < 2; ++half) {
            const int r = srow + half * 64;
            gload16(Y  + (size_t)(m0 + r) * 1024 + k0 + scol,
                    As + half * 2048 + w * 512);
            gload16(Wt + (size_t)(n0 + r) * 1024 + k0 + scol,
                    Bs + half * 2048 + w * 512);
        }
        __syncthreads();

        bf16x8 af[4], bfr[4];
#pragma unroll
        for (int m = 0; m < 4; ++m)
            af[m] = *(const bf16x8*)(As + (wr + m * 16 + lr) * 32 + lg * 8);
#pragma unroll
        for (int n = 0; n < 4; ++n)
            bfr[n] = *(const bf16x8*)(Bs + (wc + n * 16 + lr) * 32 + lg * 8);
#pragma unroll
        for (int m = 0; m < 4; ++m)
#pragma unroll
            for (int n = 0; n < 4; ++n)
                acc[m][n] = MFMA16(af[m], bfr[n], acc[m][n]);
        __syncthreads();
    }

#pragma unroll
    for (int m = 0; m < 4; ++m)
#pragma unroll
        for (int n = 0; n < 4; ++n)
#pragma unroll
            for (int j = 0; j < 4; ++j) {
                int gm = m0 + wr + m * 16 + lg * 4 + j;
                int gn = n0 + wc + n * 16 + lr;
                Out[(size_t)gm * 1024 + gn] = acc[m][n][j] + bias[gn];
            }
}

// ---------------------------------------------------------------------------
extern "C" void kernel_launch(void* const* d_in, const int* in_sizes, int n_in,
                              void* d_out, int out_size, void* d_ws, size_t ws_size,
                              hipStream_t stream)
{
    const float* x     = (const float*)d_in[0];
    const float* w_qkv = (const float*)d_in[1];
    const float* b_qkv = (const float*)d_in[2];
    const float* w_out = (const float*)d_in[3];
    const float* b_out = (const float*)d_in[4];
    float* out = (float*)d_out;

    char* ws = (char*)d_ws;
    bf16* wqkvT = (bf16*)(ws);                                      //  6.29 MB
    bf16* woutT = (bf16*)(ws + 6291456);                            //  2.10 MB
    bf16* Qb    = (bf16*)(ws + 6291456 + 2097152);                  // 16.78 MB
    bf16* Kb    = (bf16*)(ws + 6291456 + 2097152 + 16777216);       // 16.78 MB
    bf16* Vt    = (bf16*)(ws + 6291456 + 2097152 + 2u * 16777216u); // 16.78 MB
    bf16* Xb    = (bf16*)(ws + 6291456 + 2097152 + 3u * 16777216u); // 16.78 MB
    bf16* Yb    = Xb;  // alias: Xb dead before attn writes Yb

    xcast<<<2048, 256, 0, stream>>>(x, Xb);
    cast_transpose<<<dim3(96, 32), 256, 0, stream>>>(w_qkv, wqkvT, 1024, 3072);
    cast_transpose<<<dim3(32, 32), 256, 0, stream>>>(w_out, woutT, 1024, 1024);
    qkv_gemm<<<dim3(64, 24), 256, 0, stream>>>(Xb, wqkvT, b_qkv, Qb, Kb, Vt);
    attn<<<1024, 512, 0, stream>>>(Qb, Kb, Vt, Yb);
    out_gemm<<<dim3(64, 8), 256, 0, stream>>>(Yb, woutT, b_out, out);
}

// Round 24
// 171.973 us; speedup vs baseline: 1.0874x; 1.0874x over previous
//
#include <hip/hip_runtime.h>
#include <hip/hip_bf16.h>

typedef __bf16 bf16;
typedef __attribute__((__ext_vector_type__(4))) __bf16 bf16x4;
typedef __attribute__((__ext_vector_type__(8))) __bf16 bf16x8;
typedef __attribute__((__ext_vector_type__(4))) float f32x4;

#define MFMA16(a, b, c) __builtin_amdgcn_mfma_f32_16x16x32_bf16(a, b, c, 0, 0, 0)

static __device__ __forceinline__ bf16 f2b(float f) { return (bf16)f; }

// async global->LDS, 16B per lane. LDS dest: wave-uniform base + lane*16 (HW).
static __device__ __forceinline__ void gload16(const void* g, void* l) {
    __builtin_amdgcn_global_load_lds(
        (const __attribute__((address_space(1))) int*)g,
        (__attribute__((address_space(3))) int*)l, 16, 0, 0);
}

// ---------------------------------------------------------------------------
// xcast: f32 -> bf16 bulk cast (X -> Xb), 16 elems/thread
// ---------------------------------------------------------------------------
__global__ __launch_bounds__(256) void xcast(
    const float* __restrict__ in, bf16* __restrict__ out)
{
    size_t i = ((size_t)blockIdx.x * 256 + threadIdx.x) * 16;
    float4 a0 = *(const float4*)(in + i);
    float4 a1 = *(const float4*)(in + i + 4);
    float4 a2 = *(const float4*)(in + i + 8);
    float4 a3 = *(const float4*)(in + i + 12);
    bf16x8 p0, p1;
    p0[0] = f2b(a0.x); p0[1] = f2b(a0.y); p0[2] = f2b(a0.z); p0[3] = f2b(a0.w);
    p0[4] = f2b(a1.x); p0[5] = f2b(a1.y); p0[6] = f2b(a1.z); p0[7] = f2b(a1.w);
    p1[0] = f2b(a2.x); p1[1] = f2b(a2.y); p1[2] = f2b(a2.z); p1[3] = f2b(a2.w);
    p1[4] = f2b(a3.x); p1[5] = f2b(a3.y); p1[6] = f2b(a3.z); p1[7] = f2b(a3.w);
    *(bf16x8*)(out + i) = p0;
    *(bf16x8*)(out + i + 8) = p1;
}

// ---------------------------------------------------------------------------
// fused cast+transpose for BOTH weights: z=0 -> w_qkv (1024x3072),
// z=1 -> w_out (1024x1024, only x<32 blocks active)
// ---------------------------------------------------------------------------
__global__ __launch_bounds__(256) void wt_transpose(
    const float* __restrict__ wqkv, bf16* __restrict__ wqkvT,
    const float* __restrict__ wout, bf16* __restrict__ woutT)
{
    const int z = blockIdx.z;
    if (z == 1 && blockIdx.x >= 32) return;
    const float* in = z ? wout : wqkv;
    bf16* out = z ? woutT : wqkvT;
    const int Cc = z ? 1024 : 3072;
    const int R = 1024;

    __shared__ float tile[32][33];
    const int c0 = blockIdx.x * 32, r0 = blockIdx.y * 32;
    const int tx = threadIdx.x & 31, ty = threadIdx.x >> 5;
#pragma unroll
    for (int i = ty; i < 32; i += 8)
        tile[i][tx] = in[(size_t)(r0 + i) * Cc + c0 + tx];
    __syncthreads();
#pragma unroll
    for (int i = ty; i < 32; i += 8)
        out[(size_t)(c0 + i) * R + r0 + tx] = f2b(tile[tx][i]);
}

// ---------------------------------------------------------------------------
// QKV GEMM (m97-style): Xb (8192x1024 bf16) @ WqkvT^T + bias -> Qb,Kb,Vt
//   Q is PRE-SCALED by 1/sqrt(64)*log2(e) so attn works in log2 domain free.
// ---------------------------------------------------------------------------
#define QSCALE (0.125f * 1.44269504f)

__global__ __launch_bounds__(256) void qkv_gemm(
    const bf16* __restrict__ Xb, const bf16* __restrict__ Wt,
    const float* __restrict__ bias,
    bf16* __restrict__ Qb, bf16* __restrict__ Kb, bf16* __restrict__ Vt)
{
    __shared__ __align__(16) bf16 As[128 * 32];
    __shared__ __align__(16) bf16 Bs[128 * 32];
    const int m0 = blockIdx.x * 128, n0 = blockIdx.y * 128;
    const int tid = threadIdx.x, lane = tid & 63, w = tid >> 6;
    const int wr = (w >> 1) * 64, wc = (w & 1) * 64;
    const int lg = lane >> 4, lr = lane & 15;
    const int srow = tid >> 2, scol = (tid & 3) * 8;
    f32x4 acc[4][4] = {};

    for (int k0 = 0; k0 < 1024; k0 += 32) {
#pragma unroll
        for (int half = 0; half < 2; ++half) {
            const int r = srow + half * 64;
            gload16(Xb + (size_t)(m0 + r) * 1024 + k0 + scol,
                    As + half * 2048 + w * 512);
            gload16(Wt + (size_t)(n0 + r) * 1024 + k0 + scol,
                    Bs + half * 2048 + w * 512);
        }
        __syncthreads();

        bf16x8 af[4], bfr[4];
#pragma unroll
        for (int m = 0; m < 4; ++m)
            af[m] = *(const bf16x8*)(As + (wr + m * 16 + lr) * 32 + lg * 8);
#pragma unroll
        for (int n = 0; n < 4; ++n)
            bfr[n] = *(const bf16x8*)(Bs + (wc + n * 16 + lr) * 32 + lg * 8);
#pragma unroll
        for (int m = 0; m < 4; ++m)
#pragma unroll
            for (int n = 0; n < 4; ++n)
                acc[m][n] = MFMA16(af[m], bfr[n], acc[m][n]);
        __syncthreads();
    }

#pragma unroll
    for (int m = 0; m < 4; ++m)
#pragma unroll
        for (int n = 0; n < 4; ++n) {
            int gn = n0 + wc + n * 16 + lr;
            int which = gn >> 10, cc = gn & 1023;
            int h = cc >> 6, d = cc & 63;
            float bv = bias[gn];
            if (which == 2) {
                int gm0 = m0 + wr + m * 16 + lg * 4;
                int b = gm0 >> 11, t0 = gm0 & 2047;
                size_t bh = (size_t)(b * 16 + h);
                bf16x4 pk;
#pragma unroll
                for (int j = 0; j < 4; ++j) pk[j] = f2b(acc[m][n][j] + bv);
                *(bf16x4*)(Vt + (bh * 64 + d) * 2048 + t0) = pk;
            } else {
#pragma unroll
                for (int j = 0; j < 4; ++j) {
                    int gm = m0 + wr + m * 16 + lg * 4 + j;
                    int b = gm >> 11, t = gm & 2047;
                    size_t bh = (size_t)(b * 16 + h);
                    if (which == 0)
                        Qb[(bh * 2048 + t) * 64 + d] =
                            f2b((acc[m][n][j] + bv) * QSCALE);
                    else
                        Kb[(bh * 2048 + t) * 64 + d] = f2b(acc[m][n][j] + bv);
                }
            }
        }
}

// ---------------------------------------------------------------------------
// Flash attention (causal), triangle-paired, swapped QK^T, XCD-colocated.
// KVBLK=128 (R22-verified best): stage TWO 64-key sub-tiles per barrier pair.
// Swizzled [128][64] K/V; no-max softmax; l via ones-MFMA; T5 setprio.
// LDS = 16K+16K+8K = 40960 B -> 4 blocks/CU.
// ---------------------------------------------------------------------------
__global__ __launch_bounds__(256, 4) void attn(
    const bf16* __restrict__ Qb, const bf16* __restrict__ Kb,
    const bf16* __restrict__ Vt, bf16* __restrict__ Yb)
{
    __shared__ __align__(16) bf16 Ks[2 * 64 * 64];
    __shared__ __align__(16) bf16 Vs[2 * 64 * 64];
    __shared__ __align__(16) bf16 Ps[4][16 * 64];
    const int lid = blockIdx.x;                  // 0..1023
    const int xcd = lid & 7, idx = lid >> 3;     // round-robin XCD assumption
    const int bh = xcd * 8 + (idx >> 4);         // 8 bh per XCD
    const int pair = idx & 15;                   // 0..15
    const int ia = pair, ib = 31 - pair;
    const int q0A = ia * 64, q0B = ib * 64;
    const int tid = threadIdx.x, lane = tid & 63, w = tid >> 6;
    const int lg = lane >> 4, lr = lane & 15;

    const bf16* qrA = Qb + ((size_t)bh * 2048 + q0A + w * 16 + lr) * 64;
    bf16x8 qA0 = *(const bf16x8*)(qrA + lg * 8);
    bf16x8 qA1 = *(const bf16x8*)(qrA + 32 + lg * 8);
    const bf16* qrB = Qb + ((size_t)bh * 2048 + q0B + w * 16 + lr) * 64;
    bf16x8 qB0 = *(const bf16x8*)(qrB + lg * 8);
    bf16x8 qB1 = *(const bf16x8*)(qrB + 32 + lg * 8);

    const bf16 one = (bf16)1.0f;
    const bf16x8 vones = {one, one, one, one, one, one, one, one};

    f32x4 oA[4] = {}, oB[4] = {};                // o[n][j]: d=n*16+lr, q=w*16+lg*4+j
    f32x4 oLA = {}, oLB = {};                    // l accumulators (ones-MFMA)

    // staging constants (verified): per 64x64 sub-tile, stride-64 rows
    const int sr = tid >> 2;
    const int c0 = (tid & 3) * 2;
    const int sp = c0 * 8;                                   // source elems
    const int d0 = sr * 64 + ((c0 ^ (sr & 7)) << 3);         // dest elems
    const int d1 = sr * 64 + (((c0 + 1) ^ (sr & 7)) << 3);
    // read-side swizzled column offsets; row&7 == lr&7
    const int swa = ((lg ^ (lr & 7)) << 3);
    const int swb = (((lg + 4) ^ (lr & 7)) << 3);
    // Ps write slot (verified)
    const int pbase = lr * 64 + (lg & 1) * 4;

    auto stage = [&](int j0, bf16* Kd, bf16* Vd) {
        const bf16* ksrc = Kb + ((size_t)bh * 2048 + j0 + sr) * 64 + sp;
        int4 k0r = *(const int4*)ksrc;
        int4 k1r = *(const int4*)(ksrc + 8);
        const bf16* vsrc = Vt + ((size_t)bh * 64 + sr) * 2048 + j0 + sp;
        int4 v0r = *(const int4*)vsrc;
        int4 v1r = *(const int4*)(vsrc + 8);
        *(int4*)(Kd + d0) = k0r;
        *(int4*)(Kd + d1) = k1r;
        *(int4*)(Vd + d0) = v0r;
        *(int4*)(Vd + d1) = v1r;
    };

    // P-frag build via per-wave swizzled LDS. No max tracking.
    auto sm = [&](f32x4 (&s)[4], bool diag, bf16x8& pf0, bf16x8& pf1) {
        if (diag) {
            const int qloc = w * 16 + lr;
#pragma unroll
            for (int n = 0; n < 4; ++n)
#pragma unroll
                for (int j = 0; j < 4; ++j)
                    if (n * 16 + lg * 4 + j > qloc) s[n][j] = -1e30f;
        }
#pragma unroll
        for (int n = 0; n < 4; ++n) {
            bf16x4 pk;
#pragma unroll
            for (int j = 0; j < 4; ++j)
                pk[j] = f2b(exp2f(s[n][j]));
            *(bf16x4*)(&Ps[w][pbase + (((n * 2 + (lg >> 1)) ^ (lr & 7)) << 3)]) = pk;
        }
        pf0 = *(const bf16x8*)(&Ps[w][lr * 64 + swa]);
        pf1 = *(const bf16x8*)(&Ps[w][lr * 64 + swb]);
    };

    // one full compute phase for KV sub-tile in (Kr,Vr), tile index t
    auto phase2 = [&](int t, const bf16* Kr, const bf16* Vr) {
        const bool doA = (t <= ia);
        f32x4 sA[4], sB[4];
        __builtin_amdgcn_s_setprio(1);
#pragma unroll
        for (int n = 0; n < 4; ++n) {
            const bf16* krow = Kr + (n * 16 + lr) * 64;
            bf16x8 kf0 = *(const bf16x8*)(krow + swa);
            bf16x8 kf1 = *(const bf16x8*)(krow + swb);
            f32x4 zb = {};
            zb = MFMA16(kf0, qB0, zb);
            zb = MFMA16(kf1, qB1, zb);
            sB[n] = zb;
            if (doA) {
                f32x4 za = {};
                za = MFMA16(kf0, qA0, za);
                za = MFMA16(kf1, qA1, za);
                sA[n] = za;
            }
        }
        __builtin_amdgcn_s_setprio(0);

        bf16x8 pfB0, pfB1, pfA0, pfA1;
        sm(sB, t == ib, pfB0, pfB1);
        if (doA) sm(sA, t == ia, pfA0, pfA1);

        __builtin_amdgcn_s_setprio(1);
        oLB = MFMA16(pfB0, vones, oLB);
        oLB = MFMA16(pfB1, vones, oLB);
        if (doA) {
            oLA = MFMA16(pfA0, vones, oLA);
            oLA = MFMA16(pfA1, vones, oLA);
        }
#pragma unroll
        for (int n = 0; n < 4; ++n) {
            const bf16* vrow = Vr + (n * 16 + lr) * 64;
            bf16x8 vf0 = *(const bf16x8*)(vrow + swa);
            bf16x8 vf1 = *(const bf16x8*)(vrow + swb);
            oB[n] = MFMA16(pfB0, vf0, oB[n]);
            oB[n] = MFMA16(pfB1, vf1, oB[n]);
            if (doA) {
                oA[n] = MFMA16(pfA0, vf0, oA[n]);
                oA[n] = MFMA16(pfA1, vf1, oA[n]);
            }
        }
        __builtin_amdgcn_s_setprio(0);
    };

    const int ntiles = ib + 1;                   // 17..32
    for (int t0 = 0; t0 < ntiles; t0 += 2) {
        const int t1 = t0 + 1;
        const bool has1 = (t1 < ntiles);
        stage(t0 * 64, Ks, Vs);
        stage((has1 ? t1 : t0) * 64, Ks + 4096, Vs + 4096);  // clamp duplicate
        __syncthreads();

        phase2(t0, Ks, Vs);
        if (has1) phase2(t1, Ks + 4096, Vs + 4096);
        __syncthreads();
    }

    const int b = bh >> 4, h = bh & 15;
    auto wout = [&](f32x4 (&o)[4], f32x4& oL, int q0) {
        float lj[4];
#pragma unroll
        for (int j = 0; j < 4; ++j) lj[j] = 1.f / oL[j];
#pragma unroll
        for (int n = 0; n < 4; ++n)
#pragma unroll
            for (int j = 0; j < 4; ++j) {
                int qr = q0 + w * 16 + lg * 4 + j;
                Yb[((size_t)b * 2048 + qr) * 1024 + h * 64 + n * 16 + lr] =
                    f2b(o[n][j] * lj[j]);
            }
    };
    wout(oA, oLA, q0A);
    wout(oB, oLB, q0B);
}

// ---------------------------------------------------------------------------
// Out GEMM (m97-style): Yb (8192x1024 bf16) @ WoutT^T + bias -> Out f32
// ---------------------------------------------------------------------------
__global__ __launch_bounds__(256) void out_gemm(
    const bf16* __restrict__ Y, const bf16* __restrict__ Wt,
    const float* __restrict__ bias, float* __restrict__ Out)
{
    __shared__ __align__(16) bf16 As[128 * 32];
    __shared__ __align__(16) bf16 Bs[128 * 32];
    const int m0 = blockIdx.x * 128, n0 = blockIdx.y * 128;
    const int tid = threadIdx.x, lane = tid & 63, w = tid >> 6;
    const int wr = (w >> 1) * 64, wc = (w & 1) * 64;
    const int lg = lane >> 4, lr = lane & 15;
    const int srow = tid >> 2, scol = (tid & 3) * 8;
    f32x4 acc[4][4] = {};

    for (int k0 = 0; k0 < 1024; k0 += 32) {
#pragma unroll
        for (int half = 0; half < 2; ++half) {
            const int r = srow + half * 64;
            gload16(Y  + (size_t)(m0 + r) * 1024 + k0 + scol,
                    As + half * 2048 + w * 512);
            gload16(Wt + (size_t)(n0 + r) * 1024 + k0 + scol,
                    Bs + half * 2048 + w * 512);
        }
        __syncthreads();

        bf16x8 af[4], bfr[4];
#pragma unroll
        for (int m = 0; m < 4; ++m)
            af[m] = *(const bf16x8*)(As + (wr + m * 16 + lr) * 32 + lg * 8);
#pragma unroll
        for (int n = 0; n < 4; ++n)
            bfr[n] = *(const bf16x8*)(Bs + (wc + n * 16 + lr) * 32 + lg * 8);
#pragma unroll
        for (int m = 0; m < 4; ++m)
#pragma unroll
            for (int n = 0; n < 4; ++n)
                acc[m][n] = MFMA16(af[m], bfr[n], acc[m][n]);
        __syncthreads();
    }

#pragma unroll
    for (int m = 0; m < 4; ++m)
#pragma unroll
        for (int n = 0; n < 4; ++n)
#pragma unroll
            for (int j = 0; j < 4; ++j) {
                int gm = m0 + wr + m * 16 + lg * 4 + j;
                int gn = n0 + wc + n * 16 + lr;
                Out[(size_t)gm * 1024 + gn] = acc[m][n][j] + bias[gn];
            }
}

// ---------------------------------------------------------------------------
extern "C" void kernel_launch(void* const* d_in, const int* in_sizes, int n_in,
                              void* d_out, int out_size, void* d_ws, size_t ws_size,
                              hipStream_t stream)
{
    const float* x     = (const float*)d_in[0];
    const float* w_qkv = (const float*)d_in[1];
    const float* b_qkv = (const float*)d_in[2];
    const float* w_out = (const float*)d_in[3];
    const float* b_out = (const float*)d_in[4];
    float* out = (float*)d_out;

    char* ws = (char*)d_ws;
    bf16* wqkvT = (bf16*)(ws);                                      //  6.29 MB
    bf16* woutT = (bf16*)(ws + 6291456);                            //  2.10 MB
    bf16* Qb    = (bf16*)(ws + 6291456 + 2097152);                  // 16.78 MB
    bf16* Kb    = (bf16*)(ws + 6291456 + 2097152 + 16777216);       // 16.78 MB
    bf16* Vt    = (bf16*)(ws + 6291456 + 2097152 + 2u * 16777216u); // 16.78 MB
    bf16* Xb    = (bf16*)(ws + 6291456 + 2097152 + 3u * 16777216u); // 16.78 MB
    bf16* Yb    = Xb;  // alias: Xb dead before attn writes Yb

    xcast<<<2048, 256, 0, stream>>>(x, Xb);
    wt_transpose<<<dim3(96, 32, 2), 256, 0, stream>>>(w_qkv, wqkvT, w_out, woutT);
    qkv_gemm<<<dim3(64, 24), 256, 0, stream>>>(Xb, wqkvT, b_qkv, Qb, Kb, Vt);
    attn<<<dim3(1024), 256, 0, stream>>>(Qb, Kb, Vt, Yb);
    out_gemm<<<dim3(64, 8), 256, 0, stream>>>(Yb, woutT, b_out, out);
}